// Round 5
// baseline (1597.175 us; speedup 1.0000x reference)
//
#include <hip/hip_runtime.h>
#include <math.h>

#define T_ 64
#define M_ 256
#define K_ 6
#define B_ 256
#define H_ 256
#define L_ 128
#define V_ 780
#define E_ (T_*M_)       // 16384
#define ZD 383           // H+L-1
#define UD 638           // 2H+L-2
#define KP 384           // ZD padded for MFMA
#define VP 832           // V padded to 13*64

typedef unsigned short ushort_t;
typedef __attribute__((ext_vector_type(8))) short bf16x8v;
typedef __attribute__((ext_vector_type(4))) float f32x4v;

// ---------------- helpers ----------------

__device__ __forceinline__ float blk_sum(float v, float* red) {
    int j = threadIdx.x;
    #pragma unroll
    for (int o = 32; o > 0; o >>= 1) v += __shfl_down(v, o, 64);
    __syncthreads();
    if ((j & 63) == 0) red[j >> 6] = v;
    __syncthreads();
    return red[0] + red[1] + red[2] + red[3];
}

__device__ __forceinline__ float wave_sum(float v) {
    #pragma unroll
    for (int o = 32; o > 0; o >>= 1) v += __shfl_xor(v, o, 64);
    return v;
}

__device__ __forceinline__ void wave_maxarg(float& v, int& i) {
    #pragma unroll
    for (int o = 32; o > 0; o >>= 1) {
        float vo = __shfl_xor(v, o, 64);
        int   io = __shfl_xor(i, o, 64);
        if (vo > v || (vo == v && io < i)) { v = vo; i = io; }
    }
}

__device__ __forceinline__ ushort_t f2bf(float x) {
    union { float f; unsigned int u; } a; a.f = x;
    unsigned int r = a.u + 0x7fffu + ((a.u >> 16) & 1u);
    return (ushort_t)(r >> 16);
}

// ---------------- init ----------------

__global__ __launch_bounds__(256) void init_k(float* hbuf) {
    int idx = blockIdx.x * 256 + threadIdx.x;
    if (idx < (E_ + 1) * H_) hbuf[idx] = ((idx & (H_ - 1)) == 0) ? 1.f : 0.f;
}

__global__ __launch_bounds__(256) void transpose_k(const float* __restrict__ W0,
                                                   const float* __restrict__ W1,
                                                   float* __restrict__ W0T,
                                                   float* __restrict__ W1T) {
    int idx = blockIdx.x * 256 + threadIdx.x;
    if (idx < H_ * H_) {
        int i = idx >> 8, j = idx & 255;
        W0T[idx] = W0[j * H_ + i];
    }
    int idx2 = idx - H_ * H_;
    if (idx2 >= 0 && idx2 < (2 * H_ - 1) * H_) {
        int i = idx2 >> 8, j = idx2 & 255;
        W1T[idx2] = W1[j * (2 * H_ - 1) + i];
    }
}

// convert wcls -> bf16 padded [VP][KP]
__global__ __launch_bounds__(256) void wconv(const float* __restrict__ wcls,
                                             ushort_t* __restrict__ Wb) {
    int idx = blockIdx.x * 256 + threadIdx.x;
    if (idx >= VP * KP) return;
    int v = idx / KP, k = idx - v * KP;
    float val = (v < V_ && k < ZD) ? wcls[(size_t)v * ZD + k] : 0.f;
    Wb[idx] = f2bf(val);
}

// ---------------- sequential scan step: 2 tree-nodes per block ----------------
// 128 blocks x 256 threads (4 waves). Block mp handles m0=2*mp, m1=2*mp+1 so
// the W0T/W1T streams are shared by 12 GEMV rows (halves L2 traffic, doubles
// FMA per W-load). Wave w owns i-slice; lane l owns output cols 4l..4l+3.
// Per-m arithmetic order identical to the 1-m version (same reduction tree).

__global__ __launch_bounds__(256) void scan3(int t, float* __restrict__ hbuf,
        const float* __restrict__ W0T, const float* __restrict__ b0, const float* __restrict__ s0p,
        const float* __restrict__ W1T, const float* __restrict__ b1, const float* __restrict__ s1p,
        const float* __restrict__ emb, const int* __restrict__ wid,
        const int* __restrict__ nhi, const float* __restrict__ nhw) {
    int tid = threadIdx.x;
    int w = tid >> 6, l = tid & 63;
    int mp = blockIdx.x;
    int m0 = 2 * mp, m1 = m0 + 1;

    __shared__ __align__(16) float hn[12][H_];        // 12 KB
    __shared__ __align__(16) float pw0[4][12][H_];    // 48 KB
    __shared__ __align__(16) float zz[2][512];        // 4 KB
    __shared__ __align__(16) float py2[4][2][H_];     // 8 KB
    __shared__ __align__(16) float redk[4][16];
    __shared__ float y0s[12];
    __shared__ float sca[2];

    const int*   ip0 = nhi + (t * M_ + m0) * K_;
    const float* wp0 = nhw + (t * M_ + m0) * K_;
    const int*   ip1 = nhi + (t * M_ + m1) * K_;
    const float* wp1 = nhw + (t * M_ + m1) * K_;

    // stage 12 neighbor rows
    #pragma unroll
    for (int k = 0; k < K_; k++) {
        hn[k][tid]     = hbuf[(size_t)ip0[k] * H_ + tid];
        hn[6 + k][tid] = hbuf[(size_t)ip1[k] * H_ + tid];
    }
    __syncthreads();

    // ---- W0 GEMM: y[r][j] = sum_i hn[r][i] * W0T[i][j], r = 12 rows ----
    float a0[12][4];
    #pragma unroll
    for (int r = 0; r < 12; r++)
        #pragma unroll
        for (int c = 0; c < 4; c++) a0[r][c] = 0.f;
    {
        int i0 = w * 64;
        #pragma unroll 4
        for (int i = i0; i < i0 + 64; i++) {
            float4 wv = *(const float4*)(W0T + (size_t)i * H_ + 4 * l);
            #pragma unroll
            for (int r = 0; r < 12; r++) {
                float h = hn[r][i];
                a0[r][0] += h * wv.x; a0[r][1] += h * wv.y;
                a0[r][2] += h * wv.z; a0[r][3] += h * wv.w;
            }
        }
    }
    #pragma unroll
    for (int r = 0; r < 12; r++)
        *(float4*)&pw0[w][r][4 * l] = make_float4(a0[r][0], a0[r][1], a0[r][2], a0[r][3]);
    __syncthreads();

    // reduce partials: thread tid owns col j=tid for all 12 rows
    float y[12];
    float bj = b0[tid];
    #pragma unroll
    for (int r = 0; r < 12; r++)
        y[r] = pw0[0][r][tid] + pw0[1][r][tid] + pw0[2][r][tid] + pw0[3][r][tid] + bj;

    // batched ssq reductions (one barrier for all 12)
    #pragma unroll
    for (int r = 0; r < 12; r++) {
        float c = (tid == 0) ? 0.f : y[r] * y[r];
        c = wave_sum(c);
        if (l == 0) redk[w][r] = c;
    }
    if (tid == 0) {
        #pragma unroll
        for (int r = 0; r < 12; r++) y0s[r] = y[r];
    }
    __syncthreads();

    float es0 = expf(s0p[0]);
    float ave0 = 0.f, ws0 = 0.f, ave1 = 0.f, ws1 = 0.f;
    #pragma unroll
    for (int k = 0; k < K_; k++) {
        {
            float ssq = redk[0][k] + redk[1][k] + redk[2][k] + redk[3][k];
            float tm  = es0 / (1.f + expf(-y0s[k])) + 1.1f;
            float sc  = sqrtf((tm * tm - 1.f) / fmaxf(ssq, 1e-8f));
            float h1v = (tid == 0) ? tm : y[k] * sc;
            float wk  = wp0[k];
            ave0 += wk * h1v; ws0 += wk;
        }
        {
            int r = 6 + k;
            float ssq = redk[0][r] + redk[1][r] + redk[2][r] + redk[3][r];
            float tm  = es0 / (1.f + expf(-y0s[r])) + 1.1f;
            float sc  = sqrtf((tm * tm - 1.f) / fmaxf(ssq, 1e-8f));
            float h1v = (tid == 0) ? tm : y[r] * sc;
            float wk  = wp1[k];
            ave1 += wk * h1v; ws1 += wk;
        }
    }
    ave0 /= fmaxf(ws0, 1e-8f);
    ave1 /= fmaxf(ws1, 1e-8f);

    {
        float i0c = (tid == 0) ? -ave0 * ave0 : ave0 * ave0;
        i0c = wave_sum(i0c);
        if (l == 0) redk[w][12] = i0c;
        float i1c = (tid == 0) ? -ave1 * ave1 : ave1 * ave1;
        i1c = wave_sum(i1c);
        if (l == 0) redk[w][13] = i1c;
    }
    __syncthreads();
    float inner0 = redk[0][12] + redk[1][12] + redk[2][12] + redk[3][12];
    float inner1 = redk[0][13] + redk[1][13] + redk[2][13] + redk[3][13];
    float h1m0 = ave0 / sqrtf(fmaxf(-inner0, 1e-8f));
    float h1m1 = ave1 / sqrtf(fmaxf(-inner1, 1e-8f));

    float cx0 = emb[(size_t)wid[t * M_ + m0] * H_ + tid];
    float cx1 = emb[(size_t)wid[t * M_ + m1] * H_ + tid];
    if (tid == 0) {
        zz[0][0] = sqrtf(fmaxf(cx0 * cx0 + h1m0 * h1m0 - 1.f, 1e-8f));
        zz[1][0] = sqrtf(fmaxf(cx1 * cx1 + h1m1 * h1m1 - 1.f, 1e-8f));
    } else {
        zz[0][tid] = cx0; zz[0][255 + tid] = h1m0;
        zz[1][tid] = cx1; zz[1][255 + tid] = h1m1;
    }
    __syncthreads();

    // ---- W1 GEMM: y2[m][j] = sum_i zz[m][i] * W1T[i][j] ----
    float a1[2][4] = {{0.f, 0.f, 0.f, 0.f}, {0.f, 0.f, 0.f, 0.f}};
    {
        int i0 = w * 128;
        int i1 = (i0 + 128 < 2 * H_ - 1) ? (i0 + 128) : (2 * H_ - 1);
        #pragma unroll 4
        for (int i = i0; i < i1; i++) {
            float4 wv = *(const float4*)(W1T + (size_t)i * H_ + 4 * l);
            float z0 = zz[0][i], z1 = zz[1][i];
            a1[0][0] += z0 * wv.x; a1[0][1] += z0 * wv.y;
            a1[0][2] += z0 * wv.z; a1[0][3] += z0 * wv.w;
            a1[1][0] += z1 * wv.x; a1[1][1] += z1 * wv.y;
            a1[1][2] += z1 * wv.z; a1[1][3] += z1 * wv.w;
        }
    }
    *(float4*)&py2[w][0][4 * l] = make_float4(a1[0][0], a1[0][1], a1[0][2], a1[0][3]);
    *(float4*)&py2[w][1][4 * l] = make_float4(a1[1][0], a1[1][1], a1[1][2], a1[1][3]);
    __syncthreads();

    float y20 = py2[0][0][tid] + py2[1][0][tid] + py2[2][0][tid] + py2[3][0][tid] + b1[tid];
    float y21 = py2[0][1][tid] + py2[1][1][tid] + py2[2][1][tid] + py2[3][1][tid] + b1[tid];
    {
        float c0 = (tid == 0) ? 0.f : y20 * y20;
        c0 = wave_sum(c0);
        if (l == 0) redk[w][14] = c0;
        float c1 = (tid == 0) ? 0.f : y21 * y21;
        c1 = wave_sum(c1);
        if (l == 0) redk[w][15] = c1;
    }
    if (tid == 0) { sca[0] = y20; sca[1] = y21; }
    __syncthreads();
    float ssq20 = redk[0][14] + redk[1][14] + redk[2][14] + redk[3][14];
    float ssq21 = redk[0][15] + redk[1][15] + redk[2][15] + redk[3][15];
    float es1 = expf(s1p[0]);
    {
        float tm2 = es1 / (1.f + expf(-sca[0])) + 1.1f;
        float sc2 = sqrtf((tm2 * tm2 - 1.f) / fmaxf(ssq20, 1e-8f));
        float nh  = (tid == 0) ? tm2 : y20 * sc2;
        hbuf[(size_t)(t * M_ + m0) * H_ + tid] = nh;
    }
    {
        float tm2 = es1 / (1.f + expf(-sca[1])) + 1.1f;
        float sc2 = sqrtf((tm2 * tm2 - 1.f) / fmaxf(ssq21, 1e-8f));
        float nh  = (tid == 0) ? tm2 : y21 * sc2;
        hbuf[(size_t)(t * M_ + m1) * H_ + tid] = nh;
    }
}

// ---------------- build Zb (bf16, K padded) with sign-folded z0 ----------------

__global__ __launch_bounds__(256) void zbuild2(const float* __restrict__ hbuf,
                                               const float* __restrict__ xtv,
                                               const int* __restrict__ bidx,
                                               ushort_t* __restrict__ Zb) {
    int e = blockIdx.x, j = threadIdx.x;
    int bi = bidx[e];
    ushort_t* zr = Zb + (size_t)e * KP;
    if (j == 0) {
        float nh0 = hbuf[(size_t)e * H_];
        float c0  = xtv[(size_t)bi * L_];
        float z0  = sqrtf(fmaxf(nh0 * nh0 + c0 * c0 - 1.f, 1e-8f));
        zr[0] = f2bf(-z0);   // fold the centroid's -x0*cls0 sign here
    } else {
        zr[j] = f2bf(hbuf[(size_t)e * H_ + j]);
    }
    if (j < 128) {
        int c = 256 + j;                       // 256..383
        float v = (c <= 382) ? xtv[(size_t)bi * L_ + (c - 255)] : 0.f;
        zr[c] = f2bf(v);
    }
}

// ---------------- msg scores GEMM (MFMA bf16): SC = 2 + 2*(Z @ wcls^T) + wbias ----------------

__global__ __launch_bounds__(256) void gemm_mfma(const ushort_t* __restrict__ Zb,
                                                 const ushort_t* __restrict__ Wb,
                                                 const float* __restrict__ wbias,
                                                 float* __restrict__ SC) {
    __shared__ __align__(16) ushort_t As[64][40];
    __shared__ __align__(16) ushort_t Bs[64][40];
    int tid = threadIdx.x;
    int w = tid >> 6, l = tid & 63;
    int m0 = blockIdx.x * 64;
    int n0 = blockIdx.y * 64;
    int r16 = l & 15, q8 = (l >> 4) * 8;

    int srow = tid >> 2;            // 0..63
    int schunk = (tid & 3) * 8;     // 0,8,16,24

    f32x4v acc[4];
    #pragma unroll
    for (int mt = 0; mt < 4; mt++) acc[mt] = (f32x4v){0.f, 0.f, 0.f, 0.f};

    for (int ks = 0; ks < KP / 32; ks++) {
        int k0 = ks * 32;
        __syncthreads();
        *(uint4*)&As[srow][schunk] = *(const uint4*)(Zb + (size_t)(m0 + srow) * KP + k0 + schunk);
        *(uint4*)&Bs[srow][schunk] = *(const uint4*)(Wb + (size_t)(n0 + srow) * KP + k0 + schunk);
        __syncthreads();

        bf16x8v bfr = *(const bf16x8v*)(&Bs[w * 16 + r16][q8]);
        #pragma unroll
        for (int mt = 0; mt < 4; mt++) {
            bf16x8v afr = *(const bf16x8v*)(&As[mt * 16 + r16][q8]);
            acc[mt] = __builtin_amdgcn_mfma_f32_16x16x32_bf16(afr, bfr, acc[mt], 0, 0, 0);
        }
    }

    int n = n0 + w * 16 + r16;
    if (n < V_) {
        float bias = wbias[n];
        #pragma unroll
        for (int mt = 0; mt < 4; mt++) {
            #pragma unroll
            for (int r = 0; r < 4; r++) {
                int mrow = m0 + mt * 16 + (l >> 4) * 4 + r;
                SC[(size_t)mrow * V_ + n] = 2.f + 2.f * acc[mt][r] + bias;
            }
        }
    }
}

// ---------------- msg CE (masked by direction), wave-per-row, no atomics ----------------

__global__ __launch_bounds__(256) void msg_ce2(const float* __restrict__ SC,
                                               const int* __restrict__ pt,
                                               const int* __restrict__ dir,
                                               float* __restrict__ part) {
    int w = threadIdx.x >> 6, l = threadIdx.x & 63;
    int wg = blockIdx.x * 4 + w;     // 0..1023
    float lloss = 0.f, lhit = 0.f, lpm = 0.f;
    for (int i = 0; i < 16; i++) {
        int e = wg * 16 + i;
        const float* s = SC + (size_t)e * V_;
        float sv[13];
        float mx = -1e30f; int mi = 0;
        #pragma unroll
        for (int ii = 0; ii < 13; ii++) {
            int v = l + ii * 64;
            float x = (v < V_) ? s[v] : -1e30f;
            sv[ii] = x;
            if (x > mx) { mx = x; mi = v; }
        }
        wave_maxarg(mx, mi);
        float se = 0.f;
        #pragma unroll
        for (int ii = 0; ii < 13; ii++) se += expf(sv[ii] - mx);
        se = wave_sum(se);
        if (l == 0) {
            int tgt = pt[e];
            float lse = mx + logf(se);
            float pm = (float)dir[e];
            lloss += pm * (lse - s[tgt]);
            lhit  += pm * ((mi == tgt) ? 1.f : 0.f);
            lpm   += pm;
        }
    }
    __shared__ float red[4][3];
    if (l == 0) { red[w][0] = lloss; red[w][1] = lhit; red[w][2] = lpm; }
    __syncthreads();
    if (threadIdx.x == 0) {
        float* pr = part + (size_t)blockIdx.x * 8;
        pr[0] = red[0][0] + red[1][0] + red[2][0] + red[3][0];
        pr[1] = red[0][1] + red[1][1] + red[2][1] + red[3][1];
        pr[2] = red[0][2] + red[1][2] + red[2][2] + red[3][2];
        pr[3] = 0.f; pr[4] = 0.f;
    }
}

// ---------------- stop head per message, wave-per-row, no atomics ----------------

__global__ __launch_bounds__(256) void stop_e2(const float* __restrict__ hbuf,
        const float* __restrict__ emb, const float* __restrict__ xtv,
        const int* __restrict__ wid, const int* __restrict__ noi, const float* __restrict__ now_w,
        const int* __restrict__ bidx, const int* __restrict__ dir,
        const float* __restrict__ ucls, const float* __restrict__ ubias,
        float* __restrict__ part) {
    int w = threadIdx.x >> 6, l = threadIdx.x & 63;
    int wg = blockIdx.x * 4 + w;

    float ua0[4], ub0[4], ua1[4], ub1[4], uc0[2], uc1[2];
    #pragma unroll
    for (int s = 0; s < 4; s++) {
        int j = s * 64 + l;
        ua0[s] = ucls[j];        ub0[s] = ucls[255 + j];
        ua1[s] = ucls[UD + j];   ub1[s] = ucls[UD + 255 + j];
    }
    #pragma unroll
    for (int s = 0; s < 2; s++) {
        int j = s * 64 + l;
        uc0[s] = ucls[510 + j];  uc1[s] = ucls[UD + 510 + j];
    }
    float u00 = ucls[0], u10 = ucls[UD];
    float ubs0 = ubias[0], ubs1 = ubias[1];

    float lloss = 0.f, lhit = 0.f;
    for (int i = 0; i < 16; i++) {
        int e = wg * 16 + i;
        const int*   ip = noi + e * K_;
        const float* wp = now_w + e * K_;
        float ave[4] = {0.f, 0.f, 0.f, 0.f};
        float wsum = 0.f;
        #pragma unroll
        for (int k = 0; k < K_; k++) {
            int id = ip[k]; float wt = wp[k];
            wsum += wt;
            const float* hr = hbuf + (size_t)id * H_;
            #pragma unroll
            for (int s = 0; s < 4; s++) ave[s] += wt * hr[s * 64 + l];
        }
        float inv = 1.f / fmaxf(wsum, 1e-8f);
        float innl = 0.f;
        #pragma unroll
        for (int s = 0; s < 4; s++) { ave[s] *= inv; innl += ave[s] * ave[s]; }
        if (l == 0) innl -= 2.f * ave[0] * ave[0];
        float inner = wave_sum(innl);
        float cs = 1.f / sqrtf(fmaxf(-inner, 1e-8f));

        int we = wid[e], bi = bidx[e];
        const float* er = emb + (size_t)we * H_;
        const float* cr = xtv + (size_t)bi * L_;

        float p0 = 0.f, p1 = 0.f;
        #pragma unroll
        for (int s = 0; s < 4; s++) {
            float cx = er[s * 64 + l];
            float co = ave[s] * cs;
            if (s == 0 && l == 0) {
                float ctx0 = cr[0];
                float t1sq = fmaxf(cx * cx + co * co - 1.f, 1e-8f);
                float sh0 = sqrtf(fmaxf(t1sq + ctx0 * ctx0 - 1.f, 1e-8f));
                p0 += -sh0 * u00; p1 += -sh0 * u10;
            } else {
                p0 += cx * ua0[s] + co * ub0[s];
                p1 += cx * ua1[s] + co * ub1[s];
            }
            if (s < 2) {
                int j = s * 64 + l;
                if (j >= 1) {
                    float ctx = cr[j];
                    p0 += ctx * uc0[s]; p1 += ctx * uc1[s];
                }
            }
        }
        p0 = wave_sum(p0); p1 = wave_sum(p1);
        if (l == 0) {
            float sc0 = 2.f + 2.f * p0 + ubs0;
            float sc1 = 2.f + 2.f * p1 + ubs1;
            int tgt = dir[e];
            float m = fmaxf(sc0, sc1);
            float lse = m + logf(expf(sc0 - m) + expf(sc1 - m));
            lloss += lse - ((tgt == 0) ? sc0 : sc1);
            int am = (sc1 > sc0) ? 1 : 0;
            lhit += (am == tgt) ? 1.f : 0.f;
        }
    }
    __shared__ float red[4][2];
    if (l == 0) { red[w][0] = lloss; red[w][1] = lhit; }
    __syncthreads();
    if (threadIdx.x == 0) {
        float* pr = part + (size_t)(256 + blockIdx.x) * 8;
        pr[0] = 0.f; pr[1] = 0.f; pr[2] = 0.f;
        pr[3] = red[0][0] + red[1][0] + red[2][0] + red[3][0];
        pr[4] = red[0][1] + red[1][1] + red[2][1] + red[3][1];
    }
}

// ---------------- root: stop head + pred head ----------------

__global__ __launch_bounds__(256) void root_k(const float* __restrict__ hbuf,
        const float* __restrict__ emb, const float* __restrict__ xtv,
        const int* __restrict__ rwid, const int* __restrict__ roi, const float* __restrict__ row_w,
        const float* __restrict__ wcls, const float* __restrict__ wbias,
        const float* __restrict__ ucls, const float* __restrict__ ubias,
        float* __restrict__ part) {
    int b = blockIdx.x, j = threadIdx.x;
    __shared__ float red[256];
    __shared__ int   redi[256];
    __shared__ float shs[4];
    __shared__ float ctxs[L_];
    __shared__ float sc[V_];
    float* pr = part + (size_t)(512 + b) * 8;

    const int*   ip = roi + b * K_;
    const float* wp = row_w + b * K_;
    float ave = 0.f, wsum = 0.f;
    #pragma unroll
    for (int k = 0; k < K_; k++) {
        int id = ip[k]; float w = wp[k];
        ave += w * hbuf[(size_t)id * H_ + j];
        wsum += w;
    }
    ave /= fmaxf(wsum, 1e-8f);
    float inner = blk_sum((j == 0) ? -ave * ave : ave * ave, red);
    float ro = ave / sqrtf(fmaxf(-inner, 1e-8f));

    int   rw = rwid[b];
    float er = emb[(size_t)rw * H_ + j];
    float ctxj = (j < L_) ? xtv[(size_t)b * L_ + j] : 0.f;
    if (j == 0) { shs[0] = er; shs[1] = ro; shs[2] = ctxj; }
    if (j < L_) ctxs[j] = ctxj;
    __syncthreads();
    float t1sq = fmaxf(shs[0] * shs[0] + shs[1] * shs[1] - 1.f, 1e-8f);
    float sh0  = sqrtf(fmaxf(t1sq + shs[2] * shs[2] - 1.f, 1e-8f));

    float p0, p1;
    if (j >= 1) {
        p0 = er * ucls[j] + ro * ucls[255 + j];
        p1 = er * ucls[UD + j] + ro * ucls[UD + 255 + j];
        if (j < L_) { p0 += ctxj * ucls[510 + j]; p1 += ctxj * ucls[UD + 510 + j]; }
    } else {
        p0 = -sh0 * ucls[0];
        p1 = -sh0 * ucls[UD];
    }
    float s0 = 2.f + 2.f * blk_sum(p0, red) + ubias[0];
    float s1 = 2.f + 2.f * blk_sum(p1, red) + ubias[1];
    if (j == 0) {
        float m = fmaxf(s0, s1);
        float lse = m + logf(expf(s0 - m) + expf(s1 - m));
        int am = (s1 > s0) ? 1 : 0;
        pr[3] = lse - s0;
        pr[4] = (am == 0) ? 1.f : 0.f;
    }

    float c0 = shs[2];
    float z0 = sqrtf(fmaxf(c0 * c0, 1e-8f));
    __syncthreads();
    for (int v = j; v < V_; v += 256) {
        const float* wv = wcls + (size_t)v * ZD;
        float d = -z0 * wv[0];
        for (int i = 1; i < L_; i++) d += ctxs[i] * wv[255 + i];
        sc[v] = 2.f + 2.f * d + wbias[v];
    }
    __syncthreads();
    float mx = -1e30f; int mi = 0;
    for (int v = j; v < V_; v += 256) { float x = sc[v]; if (x > mx) { mx = x; mi = v; } }
    red[j] = mx; redi[j] = mi;
    __syncthreads();
    for (int o = 128; o > 0; o >>= 1) {
        if (j < o) {
            float xo = red[j + o]; int io = redi[j + o];
            if (xo > red[j] || (xo == red[j] && io < redi[j])) { red[j] = xo; redi[j] = io; }
        }
        __syncthreads();
    }
    float gm = red[0]; int ga = redi[0];
    __syncthreads();
    float se = 0.f;
    for (int v = j; v < V_; v += 256) se += expf(sc[v] - gm);
    red[j] = se;
    __syncthreads();
    for (int o = 128; o > 0; o >>= 1) { if (j < o) red[j] += red[j + o]; __syncthreads(); }
    if (j == 0) {
        float lse = gm + logf(red[0]);
        pr[0] = lse - sc[rw];
        pr[1] = (ga == rw) ? 1.f : 0.f;
        pr[2] = 0.f;
    }
}

// ---------------- finalize ----------------

__global__ __launch_bounds__(256) void finalize2(const float* __restrict__ part,
                                                 float* __restrict__ out) {
    int j = threadIdx.x;
    __shared__ float red[256][5];
    #pragma unroll
    for (int c = 0; c < 5; c++)
        red[j][c] = part[(size_t)j * 8 + c] + part[(size_t)(j + 256) * 8 + c]
                  + part[(size_t)(j + 512) * 8 + c];
    __syncthreads();
    for (int o = 128; o > 0; o >>= 1) {
        if (j < o) {
            #pragma unroll
            for (int c = 0; c < 5; c++) red[j][c] += red[j + o][c];
        }
        __syncthreads();
    }
    if (j == 0) {
        out[0] = red[0][0] / (float)B_;
        out[1] = red[0][3] / (float)B_;
        out[2] = red[0][1] / ((float)B_ + red[0][2]);
        out[3] = red[0][4] / (float)(E_ + B_);
    }
}

// ---------------- launch ----------------

extern "C" void kernel_launch(void* const* d_in, const int* in_sizes, int n_in,
                              void* d_out, int out_size, void* d_ws, size_t ws_size,
                              hipStream_t stream) {
    const int*   wid   = (const int*)d_in[0];
    const int*   nhi   = (const int*)d_in[1];
    const float* nhw   = (const float*)d_in[2];
    const int*   noi   = (const int*)d_in[3];
    const float* now_w = (const float*)d_in[4];
    const int*   bidx  = (const int*)d_in[5];
    const int*   dir   = (const int*)d_in[6];
    const int*   pt    = (const int*)d_in[7];
    const int*   rwid  = (const int*)d_in[8];
    const int*   roi   = (const int*)d_in[9];
    const float* row_w = (const float*)d_in[10];
    const float* xtv   = (const float*)d_in[11];
    const float* emb   = (const float*)d_in[12];
    const float* W0    = (const float*)d_in[13];
    const float* b0    = (const float*)d_in[14];
    const float* s0    = (const float*)d_in[15];
    const float* W1    = (const float*)d_in[16];
    const float* b1    = (const float*)d_in[17];
    const float* s1    = (const float*)d_in[18];
    const float* wcls  = (const float*)d_in[19];
    const float* wbias = (const float*)d_in[20];
    const float* ucls  = (const float*)d_in[21];
    const float* ubias = (const float*)d_in[22];

    float* ws   = (float*)d_ws;
    float* hbuf = ws;                                          // (E+1)*256
    float* W0T  = hbuf + (size_t)(E_ + 1) * H_;                // 65536
    float* W1T  = W0T + (size_t)H_ * H_;                       // 130816
    float* SC   = W1T + (size_t)(2 * H_ - 1) * H_;             // E*V
    float* part = SC + (size_t)E_ * V_;                        // 768*8
    ushort_t* Zb = (ushort_t*)(part + 768 * 8);                // E*KP bf16
    ushort_t* Wb = Zb + (size_t)E_ * KP;                       // VP*KP bf16
    float* out  = (float*)d_out;

    init_k<<<((E_ + 1) * H_ + 255) / 256, 256, 0, stream>>>(hbuf);
    transpose_k<<<(H_ * H_ + (2 * H_ - 1) * H_ + 255) / 256, 256, 0, stream>>>(W0, W1, W0T, W1T);
    wconv<<<(VP * KP + 255) / 256, 256, 0, stream>>>(wcls, Wb);

    for (int t = 0; t < T_; t++) {
        scan3<<<M_ / 2, 256, 0, stream>>>(t, hbuf, W0T, b0, s0, W1T, b1, s1,
                                          emb, wid, nhi, nhw);
    }

    zbuild2<<<E_, 256, 0, stream>>>(hbuf, xtv, bidx, Zb);
    gemm_mfma<<<dim3(E_ / 64, VP / 64), 256, 0, stream>>>(Zb, Wb, wbias, SC);
    msg_ce2<<<256, 256, 0, stream>>>(SC, pt, dir, part);
    stop_e2<<<256, 256, 0, stream>>>(hbuf, emb, xtv, wid, noi, now_w, bidx, dir, ucls, ubias, part);
    root_k<<<B_, 256, 0, stream>>>(hbuf, emb, xtv, rwid, roi, row_w, wcls, wbias, ucls, ubias, part);
    finalize2<<<1, 256, 0, stream>>>(part, out);
}

// Round 6
// 1087.060 us; speedup vs baseline: 1.4693x; 1.4693x over previous
//
#include <hip/hip_runtime.h>
#include <math.h>

#define T_ 64
#define M_ 256
#define K_ 6
#define B_ 256
#define H_ 256
#define L_ 128
#define V_ 780
#define E_ (T_*M_)       // 16384
#define ZD 383           // H+L-1
#define UD 638           // 2H+L-2
#define KP 384           // ZD padded for MFMA
#define VP 832           // V padded to 13*64

typedef unsigned short ushort_t;
typedef __attribute__((ext_vector_type(8))) short bf16x8v;
typedef __attribute__((ext_vector_type(4))) float f32x4v;

// ---------------- helpers ----------------

__device__ __forceinline__ float blk_sum(float v, float* red) {
    int j = threadIdx.x;
    #pragma unroll
    for (int o = 32; o > 0; o >>= 1) v += __shfl_down(v, o, 64);
    __syncthreads();
    if ((j & 63) == 0) red[j >> 6] = v;
    __syncthreads();
    return red[0] + red[1] + red[2] + red[3];
}

__device__ __forceinline__ float wave_sum(float v) {
    #pragma unroll
    for (int o = 32; o > 0; o >>= 1) v += __shfl_xor(v, o, 64);
    return v;
}

__device__ __forceinline__ void wave_maxarg(float& v, int& i) {
    #pragma unroll
    for (int o = 32; o > 0; o >>= 1) {
        float vo = __shfl_xor(v, o, 64);
        int   io = __shfl_xor(i, o, 64);
        if (vo > v || (vo == v && io < i)) { v = vo; i = io; }
    }
}

__device__ __forceinline__ ushort_t f2bf(float x) {
    union { float f; unsigned int u; } a; a.f = x;
    unsigned int r = a.u + 0x7fffu + ((a.u >> 16) & 1u);
    return (ushort_t)(r >> 16);
}

// ---------------- init ----------------

__global__ __launch_bounds__(256) void init_k(float* hbuf) {
    int idx = blockIdx.x * 256 + threadIdx.x;
    if (idx < (E_ + 1) * H_) hbuf[idx] = ((idx & (H_ - 1)) == 0) ? 1.f : 0.f;
}

__global__ __launch_bounds__(256) void transpose_k(const float* __restrict__ W0,
                                                   const float* __restrict__ W1,
                                                   float* __restrict__ W0T,
                                                   float* __restrict__ W1T) {
    int idx = blockIdx.x * 256 + threadIdx.x;
    if (idx < H_ * H_) {
        int i = idx >> 8, j = idx & 255;
        W0T[idx] = W0[j * H_ + i];
    }
    int idx2 = idx - H_ * H_;
    if (idx2 >= 0 && idx2 < (2 * H_ - 1) * H_) {
        int i = idx2 >> 8, j = idx2 & 255;
        W1T[idx2] = W1[j * (2 * H_ - 1) + i];
    }
}

// convert wcls -> bf16 padded [VP][KP]
__global__ __launch_bounds__(256) void wconv(const float* __restrict__ wcls,
                                             ushort_t* __restrict__ Wb) {
    int idx = blockIdx.x * 256 + threadIdx.x;
    if (idx >= VP * KP) return;
    int v = idx / KP, k = idx - v * KP;
    float val = (v < V_ && k < ZD) ? wcls[(size_t)v * ZD + k] : 0.f;
    Wb[idx] = f2bf(val);
}

// ---------------- sequential scan step: 512 threads (8 waves) per m ----------------
// 256 blocks (1 per m, full machine) x 8 waves => 2 waves/SIMD for latency
// hiding. Waves split the i (reduction) dim 8 ways; lane l owns output cols
// 4l..4l+3. Column-phase (nonlinear) work is replicated across the two
// 256-thread halves so the j-reduction tree matches scan2 exactly.

__global__ __launch_bounds__(512) void scan4(int t, float* __restrict__ hbuf,
        const float* __restrict__ W0T, const float* __restrict__ b0, const float* __restrict__ s0p,
        const float* __restrict__ W1T, const float* __restrict__ b1, const float* __restrict__ s1p,
        const float* __restrict__ emb, const int* __restrict__ wid,
        const int* __restrict__ nhi, const float* __restrict__ nhw) {
    int tid = threadIdx.x;
    int w = tid >> 6, l = tid & 63;      // wave 0..7
    int j = tid & 255, half = tid >> 8;  // column, thread-half
    int m = blockIdx.x;

    __shared__ __align__(16) float hn[K_][H_];          // 6 KB
    __shared__ __align__(16) float pw0[8][K_][H_];      // 48 KB
    __shared__ __align__(16) float zz[512];             // 2 KB (511 used)
    __shared__ __align__(16) float py2[8][H_];          // 8 KB
    __shared__ __align__(16) float redk[4][8];
    __shared__ float y0s[K_];
    __shared__ float sca[1];

    const int*   ip = nhi + (t * M_ + m) * K_;
    const float* wp = nhw + (t * M_ + m) * K_;

    // stage neighbor rows: half 0 -> k 0..2, half 1 -> k 3..5
    #pragma unroll
    for (int k3 = 0; k3 < 3; k3++) {
        int k = half * 3 + k3;
        hn[k][j] = hbuf[(size_t)ip[k] * H_ + j];
    }
    __syncthreads();

    // ---- W0 GEMM: y[k][j] = sum_i hn[k][i] * W0T[i][j]; wave w owns 32 i's ----
    float a0[K_][4];
    #pragma unroll
    for (int k = 0; k < K_; k++)
        #pragma unroll
        for (int c = 0; c < 4; c++) a0[k][c] = 0.f;
    {
        int i0 = w * 32;
        #pragma unroll 4
        for (int i = i0; i < i0 + 32; i++) {
            float4 wv = *(const float4*)(W0T + (size_t)i * H_ + 4 * l);
            #pragma unroll
            for (int k = 0; k < K_; k++) {
                float h = hn[k][i];
                a0[k][0] += h * wv.x; a0[k][1] += h * wv.y;
                a0[k][2] += h * wv.z; a0[k][3] += h * wv.w;
            }
        }
    }
    #pragma unroll
    for (int k = 0; k < K_; k++)
        *(float4*)&pw0[w][k][4 * l] = make_float4(a0[k][0], a0[k][1], a0[k][2], a0[k][3]);
    __syncthreads();

    // reduce partials: thread owns col j (replicated across halves)
    float y[K_];
    float bj = b0[j];
    #pragma unroll
    for (int k = 0; k < K_; k++) {
        float s = pw0[0][k][j];
        #pragma unroll
        for (int ww = 1; ww < 8; ww++) s += pw0[ww][k][j];
        y[k] = s + bj;
    }

    // batched ssq reductions over j (waves 0..3 only; grouping matches scan2)
    if (tid < 256) {
        int w4 = tid >> 6;
        #pragma unroll
        for (int k = 0; k < K_; k++) {
            float c = (tid == 0) ? 0.f : y[k] * y[k];
            c = wave_sum(c);
            if (l == 0) redk[w4][k] = c;
        }
        if (tid == 0) {
            #pragma unroll
            for (int k = 0; k < K_; k++) y0s[k] = y[k];
        }
    }
    __syncthreads();

    float es0 = expf(s0p[0]);
    float ave = 0.f, wsum = 0.f;
    #pragma unroll
    for (int k = 0; k < K_; k++) {
        float ssq = redk[0][k] + redk[1][k] + redk[2][k] + redk[3][k];
        float tm  = es0 / (1.f + expf(-y0s[k])) + 1.1f;
        float sc  = sqrtf((tm * tm - 1.f) / fmaxf(ssq, 1e-8f));
        float h1v = (j == 0) ? tm : y[k] * sc;
        float wk  = wp[k];
        ave += wk * h1v; wsum += wk;
    }
    ave /= fmaxf(wsum, 1e-8f);

    if (tid < 256) {
        int w4 = tid >> 6;
        float innl = (tid == 0) ? -ave * ave : ave * ave;
        innl = wave_sum(innl);
        if (l == 0) redk[w4][6] = innl;
    }
    __syncthreads();
    float inner = redk[0][6] + redk[1][6] + redk[2][6] + redk[3][6];
    float h1m = ave / sqrtf(fmaxf(-inner, 1e-8f));

    if (tid < 256) {
        int wde = wid[t * M_ + m];
        float cx = emb[(size_t)wde * H_ + j];
        if (j == 0) {
            zz[0] = sqrtf(fmaxf(cx * cx + h1m * h1m - 1.f, 1e-8f));
        } else {
            zz[j] = cx;
            zz[255 + j] = h1m;
        }
    }
    __syncthreads();

    // ---- W1 GEMM: y2[j] = sum_i zz[i] * W1T[i][j]; wave w owns 64 i's ----
    float a1[4] = {0.f, 0.f, 0.f, 0.f};
    {
        int i0 = w * 64;
        int i1 = (i0 + 64 < 2 * H_ - 1) ? (i0 + 64) : (2 * H_ - 1);
        #pragma unroll 4
        for (int i = i0; i < i1; i++) {
            float4 wv = *(const float4*)(W1T + (size_t)i * H_ + 4 * l);
            float z = zz[i];
            a1[0] += z * wv.x; a1[1] += z * wv.y;
            a1[2] += z * wv.z; a1[3] += z * wv.w;
        }
    }
    *(float4*)&py2[w][4 * l] = make_float4(a1[0], a1[1], a1[2], a1[3]);
    __syncthreads();

    if (tid < 256) {
        int w4 = tid >> 6;
        float y2 = py2[0][j];
        #pragma unroll
        for (int ww = 1; ww < 8; ww++) y2 += py2[ww][j];
        y2 += b1[j];
        float c2 = (tid == 0) ? 0.f : y2 * y2;
        c2 = wave_sum(c2);
        if (l == 0) redk[w4][7] = c2;
        if (tid == 0) sca[0] = y2;
        __syncthreads();
        float ssq2 = redk[0][7] + redk[1][7] + redk[2][7] + redk[3][7];
        float es1  = expf(s1p[0]);
        float tm2  = es1 / (1.f + expf(-sca[0])) + 1.1f;
        float sc2  = sqrtf((tm2 * tm2 - 1.f) / fmaxf(ssq2, 1e-8f));
        float nh   = (tid == 0) ? tm2 : y2 * sc2;
        hbuf[(size_t)(t * M_ + m) * H_ + j] = nh;
    } else {
        __syncthreads();   // keep barrier counts matched across the block
    }
}

// ---------------- build Zb (bf16, K padded) with sign-folded z0 ----------------

__global__ __launch_bounds__(256) void zbuild2(const float* __restrict__ hbuf,
                                               const float* __restrict__ xtv,
                                               const int* __restrict__ bidx,
                                               ushort_t* __restrict__ Zb) {
    int e = blockIdx.x, j = threadIdx.x;
    int bi = bidx[e];
    ushort_t* zr = Zb + (size_t)e * KP;
    if (j == 0) {
        float nh0 = hbuf[(size_t)e * H_];
        float c0  = xtv[(size_t)bi * L_];
        float z0  = sqrtf(fmaxf(nh0 * nh0 + c0 * c0 - 1.f, 1e-8f));
        zr[0] = f2bf(-z0);   // fold the centroid's -x0*cls0 sign here
    } else {
        zr[j] = f2bf(hbuf[(size_t)e * H_ + j]);
    }
    if (j < 128) {
        int c = 256 + j;                       // 256..383
        float v = (c <= 382) ? xtv[(size_t)bi * L_ + (c - 255)] : 0.f;
        zr[c] = f2bf(v);
    }
}

// ---------------- msg scores GEMM (MFMA bf16): SC = 2 + 2*(Z @ wcls^T) + wbias ----------------

__global__ __launch_bounds__(256) void gemm_mfma(const ushort_t* __restrict__ Zb,
                                                 const ushort_t* __restrict__ Wb,
                                                 const float* __restrict__ wbias,
                                                 float* __restrict__ SC) {
    __shared__ __align__(16) ushort_t As[64][40];
    __shared__ __align__(16) ushort_t Bs[64][40];
    int tid = threadIdx.x;
    int w = tid >> 6, l = tid & 63;
    int m0 = blockIdx.x * 64;
    int n0 = blockIdx.y * 64;
    int r16 = l & 15, q8 = (l >> 4) * 8;

    int srow = tid >> 2;            // 0..63
    int schunk = (tid & 3) * 8;     // 0,8,16,24

    f32x4v acc[4];
    #pragma unroll
    for (int mt = 0; mt < 4; mt++) acc[mt] = (f32x4v){0.f, 0.f, 0.f, 0.f};

    for (int ks = 0; ks < KP / 32; ks++) {
        int k0 = ks * 32;
        __syncthreads();
        *(uint4*)&As[srow][schunk] = *(const uint4*)(Zb + (size_t)(m0 + srow) * KP + k0 + schunk);
        *(uint4*)&Bs[srow][schunk] = *(const uint4*)(Wb + (size_t)(n0 + srow) * KP + k0 + schunk);
        __syncthreads();

        bf16x8v bfr = *(const bf16x8v*)(&Bs[w * 16 + r16][q8]);
        #pragma unroll
        for (int mt = 0; mt < 4; mt++) {
            bf16x8v afr = *(const bf16x8v*)(&As[mt * 16 + r16][q8]);
            acc[mt] = __builtin_amdgcn_mfma_f32_16x16x32_bf16(afr, bfr, acc[mt], 0, 0, 0);
        }
    }

    int n = n0 + w * 16 + r16;
    if (n < V_) {
        float bias = wbias[n];
        #pragma unroll
        for (int mt = 0; mt < 4; mt++) {
            #pragma unroll
            for (int r = 0; r < 4; r++) {
                int mrow = m0 + mt * 16 + (l >> 4) * 4 + r;
                SC[(size_t)mrow * V_ + n] = 2.f + 2.f * acc[mt][r] + bias;
            }
        }
    }
}

// ---------------- msg CE (masked by direction), wave-per-row, no atomics ----------------

__global__ __launch_bounds__(256) void msg_ce2(const float* __restrict__ SC,
                                               const int* __restrict__ pt,
                                               const int* __restrict__ dir,
                                               float* __restrict__ part) {
    int w = threadIdx.x >> 6, l = threadIdx.x & 63;
    int wg = blockIdx.x * 4 + w;     // 0..1023
    float lloss = 0.f, lhit = 0.f, lpm = 0.f;
    for (int i = 0; i < 16; i++) {
        int e = wg * 16 + i;
        const float* s = SC + (size_t)e * V_;
        float sv[13];
        float mx = -1e30f; int mi = 0;
        #pragma unroll
        for (int ii = 0; ii < 13; ii++) {
            int v = l + ii * 64;
            float x = (v < V_) ? s[v] : -1e30f;
            sv[ii] = x;
            if (x > mx) { mx = x; mi = v; }
        }
        wave_maxarg(mx, mi);
        float se = 0.f;
        #pragma unroll
        for (int ii = 0; ii < 13; ii++) se += expf(sv[ii] - mx);
        se = wave_sum(se);
        if (l == 0) {
            int tgt = pt[e];
            float lse = mx + logf(se);
            float pm = (float)dir[e];
            lloss += pm * (lse - s[tgt]);
            lhit  += pm * ((mi == tgt) ? 1.f : 0.f);
            lpm   += pm;
        }
    }
    __shared__ float red[4][3];
    if (l == 0) { red[w][0] = lloss; red[w][1] = lhit; red[w][2] = lpm; }
    __syncthreads();
    if (threadIdx.x == 0) {
        float* pr = part + (size_t)blockIdx.x * 8;
        pr[0] = red[0][0] + red[1][0] + red[2][0] + red[3][0];
        pr[1] = red[0][1] + red[1][1] + red[2][1] + red[3][1];
        pr[2] = red[0][2] + red[1][2] + red[2][2] + red[3][2];
        pr[3] = 0.f; pr[4] = 0.f;
    }
}

// ---------------- stop head per message, wave-per-row, no atomics ----------------

__global__ __launch_bounds__(256) void stop_e2(const float* __restrict__ hbuf,
        const float* __restrict__ emb, const float* __restrict__ xtv,
        const int* __restrict__ wid, const int* __restrict__ noi, const float* __restrict__ now_w,
        const int* __restrict__ bidx, const int* __restrict__ dir,
        const float* __restrict__ ucls, const float* __restrict__ ubias,
        float* __restrict__ part) {
    int w = threadIdx.x >> 6, l = threadIdx.x & 63;
    int wg = blockIdx.x * 4 + w;

    float ua0[4], ub0[4], ua1[4], ub1[4], uc0[2], uc1[2];
    #pragma unroll
    for (int s = 0; s < 4; s++) {
        int j = s * 64 + l;
        ua0[s] = ucls[j];        ub0[s] = ucls[255 + j];
        ua1[s] = ucls[UD + j];   ub1[s] = ucls[UD + 255 + j];
    }
    #pragma unroll
    for (int s = 0; s < 2; s++) {
        int j = s * 64 + l;
        uc0[s] = ucls[510 + j];  uc1[s] = ucls[UD + 510 + j];
    }
    float u00 = ucls[0], u10 = ucls[UD];
    float ubs0 = ubias[0], ubs1 = ubias[1];

    float lloss = 0.f, lhit = 0.f;
    for (int i = 0; i < 16; i++) {
        int e = wg * 16 + i;
        const int*   ip = noi + e * K_;
        const float* wp = now_w + e * K_;
        float ave[4] = {0.f, 0.f, 0.f, 0.f};
        float wsum = 0.f;
        #pragma unroll
        for (int k = 0; k < K_; k++) {
            int id = ip[k]; float wt = wp[k];
            wsum += wt;
            const float* hr = hbuf + (size_t)id * H_;
            #pragma unroll
            for (int s = 0; s < 4; s++) ave[s] += wt * hr[s * 64 + l];
        }
        float inv = 1.f / fmaxf(wsum, 1e-8f);
        float innl = 0.f;
        #pragma unroll
        for (int s = 0; s < 4; s++) { ave[s] *= inv; innl += ave[s] * ave[s]; }
        if (l == 0) innl -= 2.f * ave[0] * ave[0];
        float inner = wave_sum(innl);
        float cs = 1.f / sqrtf(fmaxf(-inner, 1e-8f));

        int we = wid[e], bi = bidx[e];
        const float* er = emb + (size_t)we * H_;
        const float* cr = xtv + (size_t)bi * L_;

        float p0 = 0.f, p1 = 0.f;
        #pragma unroll
        for (int s = 0; s < 4; s++) {
            float cx = er[s * 64 + l];
            float co = ave[s] * cs;
            if (s == 0 && l == 0) {
                float ctx0 = cr[0];
                float t1sq = fmaxf(cx * cx + co * co - 1.f, 1e-8f);
                float sh0 = sqrtf(fmaxf(t1sq + ctx0 * ctx0 - 1.f, 1e-8f));
                p0 += -sh0 * u00; p1 += -sh0 * u10;
            } else {
                p0 += cx * ua0[s] + co * ub0[s];
                p1 += cx * ua1[s] + co * ub1[s];
            }
            if (s < 2) {
                int j = s * 64 + l;
                if (j >= 1) {
                    float ctx = cr[j];
                    p0 += ctx * uc0[s]; p1 += ctx * uc1[s];
                }
            }
        }
        p0 = wave_sum(p0); p1 = wave_sum(p1);
        if (l == 0) {
            float sc0 = 2.f + 2.f * p0 + ubs0;
            float sc1 = 2.f + 2.f * p1 + ubs1;
            int tgt = dir[e];
            float m = fmaxf(sc0, sc1);
            float lse = m + logf(expf(sc0 - m) + expf(sc1 - m));
            lloss += lse - ((tgt == 0) ? sc0 : sc1);
            int am = (sc1 > sc0) ? 1 : 0;
            lhit += (am == tgt) ? 1.f : 0.f;
        }
    }
    __shared__ float red[4][2];
    if (l == 0) { red[w][0] = lloss; red[w][1] = lhit; }
    __syncthreads();
    if (threadIdx.x == 0) {
        float* pr = part + (size_t)(256 + blockIdx.x) * 8;
        pr[0] = 0.f; pr[1] = 0.f; pr[2] = 0.f;
        pr[3] = red[0][0] + red[1][0] + red[2][0] + red[3][0];
        pr[4] = red[0][1] + red[1][1] + red[2][1] + red[3][1];
    }
}

// ---------------- root: stop head + pred head ----------------

__global__ __launch_bounds__(256) void root_k(const float* __restrict__ hbuf,
        const float* __restrict__ emb, const float* __restrict__ xtv,
        const int* __restrict__ rwid, const int* __restrict__ roi, const float* __restrict__ row_w,
        const float* __restrict__ wcls, const float* __restrict__ wbias,
        const float* __restrict__ ucls, const float* __restrict__ ubias,
        float* __restrict__ part) {
    int b = blockIdx.x, j = threadIdx.x;
    __shared__ float red[256];
    __shared__ int   redi[256];
    __shared__ float shs[4];
    __shared__ float ctxs[L_];
    __shared__ float sc[V_];
    float* pr = part + (size_t)(512 + b) * 8;

    const int*   ip = roi + b * K_;
    const float* wp = row_w + b * K_;
    float ave = 0.f, wsum = 0.f;
    #pragma unroll
    for (int k = 0; k < K_; k++) {
        int id = ip[k]; float w = wp[k];
        ave += w * hbuf[(size_t)id * H_ + j];
        wsum += w;
    }
    ave /= fmaxf(wsum, 1e-8f);
    float inner = blk_sum((j == 0) ? -ave * ave : ave * ave, red);
    float ro = ave / sqrtf(fmaxf(-inner, 1e-8f));

    int   rw = rwid[b];
    float er = emb[(size_t)rw * H_ + j];
    float ctxj = (j < L_) ? xtv[(size_t)b * L_ + j] : 0.f;
    if (j == 0) { shs[0] = er; shs[1] = ro; shs[2] = ctxj; }
    if (j < L_) ctxs[j] = ctxj;
    __syncthreads();
    float t1sq = fmaxf(shs[0] * shs[0] + shs[1] * shs[1] - 1.f, 1e-8f);
    float sh0  = sqrtf(fmaxf(t1sq + shs[2] * shs[2] - 1.f, 1e-8f));

    float p0, p1;
    if (j >= 1) {
        p0 = er * ucls[j] + ro * ucls[255 + j];
        p1 = er * ucls[UD + j] + ro * ucls[UD + 255 + j];
        if (j < L_) { p0 += ctxj * ucls[510 + j]; p1 += ctxj * ucls[UD + 510 + j]; }
    } else {
        p0 = -sh0 * ucls[0];
        p1 = -sh0 * ucls[UD];
    }
    float s0 = 2.f + 2.f * blk_sum(p0, red) + ubias[0];
    float s1 = 2.f + 2.f * blk_sum(p1, red) + ubias[1];
    if (j == 0) {
        float m = fmaxf(s0, s1);
        float lse = m + logf(expf(s0 - m) + expf(s1 - m));
        int am = (s1 > s0) ? 1 : 0;
        pr[3] = lse - s0;
        pr[4] = (am == 0) ? 1.f : 0.f;
    }

    float c0 = shs[2];
    float z0 = sqrtf(fmaxf(c0 * c0, 1e-8f));
    __syncthreads();
    for (int v = j; v < V_; v += 256) {
        const float* wv = wcls + (size_t)v * ZD;
        float d = -z0 * wv[0];
        for (int i = 1; i < L_; i++) d += ctxs[i] * wv[255 + i];
        sc[v] = 2.f + 2.f * d + wbias[v];
    }
    __syncthreads();
    float mx = -1e30f; int mi = 0;
    for (int v = j; v < V_; v += 256) { float x = sc[v]; if (x > mx) { mx = x; mi = v; } }
    red[j] = mx; redi[j] = mi;
    __syncthreads();
    for (int o = 128; o > 0; o >>= 1) {
        if (j < o) {
            float xo = red[j + o]; int io = redi[j + o];
            if (xo > red[j] || (xo == red[j] && io < redi[j])) { red[j] = xo; redi[j] = io; }
        }
        __syncthreads();
    }
    float gm = red[0]; int ga = redi[0];
    __syncthreads();
    float se = 0.f;
    for (int v = j; v < V_; v += 256) se += expf(sc[v] - gm);
    red[j] = se;
    __syncthreads();
    for (int o = 128; o > 0; o >>= 1) { if (j < o) red[j] += red[j + o]; __syncthreads(); }
    if (j == 0) {
        float lse = gm + logf(red[0]);
        pr[0] = lse - sc[rw];
        pr[1] = (ga == rw) ? 1.f : 0.f;
        pr[2] = 0.f;
    }
}

// ---------------- finalize ----------------

__global__ __launch_bounds__(256) void finalize2(const float* __restrict__ part,
                                                 float* __restrict__ out) {
    int j = threadIdx.x;
    __shared__ float red[256][5];
    #pragma unroll
    for (int c = 0; c < 5; c++)
        red[j][c] = part[(size_t)j * 8 + c] + part[(size_t)(j + 256) * 8 + c]
                  + part[(size_t)(j + 512) * 8 + c];
    __syncthreads();
    for (int o = 128; o > 0; o >>= 1) {
        if (j < o) {
            #pragma unroll
            for (int c = 0; c < 5; c++) red[j][c] += red[j + o][c];
        }
        __syncthreads();
    }
    if (j == 0) {
        out[0] = red[0][0] / (float)B_;
        out[1] = red[0][3] / (float)B_;
        out[2] = red[0][1] / ((float)B_ + red[0][2]);
        out[3] = red[0][4] / (float)(E_ + B_);
    }
}

// ---------------- launch ----------------

extern "C" void kernel_launch(void* const* d_in, const int* in_sizes, int n_in,
                              void* d_out, int out_size, void* d_ws, size_t ws_size,
                              hipStream_t stream) {
    const int*   wid   = (const int*)d_in[0];
    const int*   nhi   = (const int*)d_in[1];
    const float* nhw   = (const float*)d_in[2];
    const int*   noi   = (const int*)d_in[3];
    const float* now_w = (const float*)d_in[4];
    const int*   bidx  = (const int*)d_in[5];
    const int*   dir   = (const int*)d_in[6];
    const int*   pt    = (const int*)d_in[7];
    const int*   rwid  = (const int*)d_in[8];
    const int*   roi   = (const int*)d_in[9];
    const float* row_w = (const float*)d_in[10];
    const float* xtv   = (const float*)d_in[11];
    const float* emb   = (const float*)d_in[12];
    const float* W0    = (const float*)d_in[13];
    const float* b0    = (const float*)d_in[14];
    const float* s0    = (const float*)d_in[15];
    const float* W1    = (const float*)d_in[16];
    const float* b1    = (const float*)d_in[17];
    const float* s1    = (const float*)d_in[18];
    const float* wcls  = (const float*)d_in[19];
    const float* wbias = (const float*)d_in[20];
    const float* ucls  = (const float*)d_in[21];
    const float* ubias = (const float*)d_in[22];

    float* ws   = (float*)d_ws;
    float* hbuf = ws;                                          // (E+1)*256
    float* W0T  = hbuf + (size_t)(E_ + 1) * H_;                // 65536
    float* W1T  = W0T + (size_t)H_ * H_;                       // 130816
    float* SC   = W1T + (size_t)(2 * H_ - 1) * H_;             // E*V
    float* part = SC + (size_t)E_ * V_;                        // 768*8
    ushort_t* Zb = (ushort_t*)(part + 768 * 8);                // E*KP bf16
    ushort_t* Wb = Zb + (size_t)E_ * KP;                       // VP*KP bf16
    float* out  = (float*)d_out;

    init_k<<<((E_ + 1) * H_ + 255) / 256, 256, 0, stream>>>(hbuf);
    transpose_k<<<(H_ * H_ + (2 * H_ - 1) * H_ + 255) / 256, 256, 0, stream>>>(W0, W1, W0T, W1T);
    wconv<<<(VP * KP + 255) / 256, 256, 0, stream>>>(wcls, Wb);

    for (int t = 0; t < T_; t++) {
        scan4<<<M_, 512, 0, stream>>>(t, hbuf, W0T, b0, s0, W1T, b1, s1,
                                      emb, wid, nhi, nhw);
    }

    zbuild2<<<E_, 256, 0, stream>>>(hbuf, xtv, bidx, Zb);
    gemm_mfma<<<dim3(E_ / 64, VP / 64), 256, 0, stream>>>(Zb, Wb, wbias, SC);
    msg_ce2<<<256, 256, 0, stream>>>(SC, pt, dir, part);
    stop_e2<<<256, 256, 0, stream>>>(hbuf, emb, xtv, wid, noi, now_w, bidx, dir, ucls, ubias, part);
    root_k<<<B_, 256, 0, stream>>>(hbuf, emb, xtv, rwid, roi, row_w, wcls, wbias, ucls, ubias, part);
    finalize2<<<1, 256, 0, stream>>>(part, out);
}